// Round 10
// baseline (100.995 us; speedup 1.0000x reference)
//
#include <hip/hip_runtime.h>

#define B_ 32
#define N_ 1024
#define NEG 0.01f
#define QSC (1.4426950408889634f/32.0f)   // log2(e)/E folded into staged Wq/bq

using half8  = __attribute__((ext_vector_type(8))) _Float16;
using half4  = __attribute__((ext_vector_type(4))) _Float16;
using half2  = __attribute__((ext_vector_type(2))) _Float16;
using fp16x2 = __attribute__((ext_vector_type(2))) __fp16;
using floatx4 = __attribute__((ext_vector_type(4))) float;

#if defined(__has_builtin)
#if __has_builtin(__builtin_amdgcn_exp2f)
#define EXP2(x) __builtin_amdgcn_exp2f(x)
#endif
#endif
#ifndef EXP2
#define EXP2(x) exp2f(x)
#endif

#define MFMA32 __builtin_amdgcn_mfma_f32_16x16x32_f16
#define MFMA16 __builtin_amdgcn_mfma_f32_16x16x16f16

__device__ inline half2 pkcvt(float a, float b) {
    fp16x2 r = __builtin_amdgcn_cvt_pkrtz(a, b);
    return __builtin_bit_cast(half2, r);
}

__device__ inline half8 cvt8(float4 a, float4 b) {
    half2 p0 = pkcvt(a.x, a.y);
    half2 p1 = pkcvt(a.z, a.w);
    half2 p2 = pkcvt(b.x, b.y);
    half2 p3 = pkcvt(b.z, b.w);
    half8 h = { p0[0],p0[1], p1[0],p1[1], p2[0],p2[1], p3[0],p3[1] };
    return h;
}

// 512 threads = 8 waves x 16 q-rows (was 4 x 32). Same grid (512 blocks ->
// 2 blocks/CU), so waves/CU doubles: 8 -> 16 (4/SIMD). Round-3's 8-wave
// attempt spilled under the old dataflow; round-9's register discipline
// (one Q-frag, one acc pair, interleaved proj, merged prologue, K-bias drop,
// vown in regs) cuts per-wave demand to ~85 < cap 128 ((512,2) -> 256/2).
// LDS unchanged 43.5KB; falsifier for spill: WRITE_SIZE >> 9MB.
struct __align__(16) Smem {
    _Float16 wsh[96*36];       // 6912B: Wq(pre-scaled)/Wk/Wv, stride 36
    float    bsh[96];          // 384B
    union {
        struct {
            _Float16 Kst[2][128*36];   // ping-pong K tile [kpos][e]; Kst[1]=qs pre-loop
            _Float16 Vtst[2][32*136];  // ping-pong Vt tile [e][kpos]
        } a;
        _Float16 xs[128*72];           // epilogue MLP input [q][ v(32) | attn(32) ]
    } u;
    float bl1[32], bl10[32], bl11[32];
};  // 43520 B

__global__ __launch_bounds__(512, 2) void fused_kernel(
    const float* __restrict__ x, const float* __restrict__ w_qkv, const float* __restrict__ b_qkv,
    const float* __restrict__ w_h1,  const float* __restrict__ b_h1,
    const float* __restrict__ w_h10, const float* __restrict__ b_h10,
    const float* __restrict__ w_h11, const float* __restrict__ b_h11,
    float* __restrict__ out)
{
    __shared__ Smem sm;
    int t = threadIdx.x;
    int bid = blockIdx.x;
    // XCD-affine remap: all 8 q-tile blocks of one bg land on the same XCD
    int xcd = bid & 7, j = bid >> 3;
    int bg = xcd*8 + (j >> 3);
    int qtile = j & 7;
    int b = bg >> 1, g = bg & 1;
    int qbase = qtile * 128;
    int lane = t & 63, w = t >> 6;          // w in 0..7, wave owns rows w*16..w*16+15
    int L15 = lane & 15, quad = lane >> 4;
    const floatx4 zz = {0.f,0.f,0.f,0.f};

    // ---- stage qkv weights (Q rows pre-scaled by QSC) + biases ----
    for (int idx = t; idx < 96*32; idx += 512) {
        int r = idx >> 5, c = idx & 31;
        float wv = w_qkv[(g*96 + r)*32 + c];
        sm.wsh[r*36 + c] = (_Float16)(r < 32 ? wv*QSC : wv);
    }
    if (t < 96) sm.bsh[t] = b_qkv[g*96 + t];
    if (t < 32) {
        sm.bl1[t]  = b_h1[g*32+t];
        sm.bl10[t] = b_h10[g*32+t];
        sm.bl11[t] = b_h11[g*32+t];
    }
    __syncthreads();

    // ---- weight B-frags + bias seeds (K bias dropped: shift-invariant) ----
    half8 bwq[2], bwk[2], bwv[2];
    floatx4 cv[2];
    #pragma unroll
    for (int et = 0; et < 2; et++) {
        bwq[et] = *(const half8*)&sm.wsh[(     et*16 + L15)*36 + quad*8];
        bwk[et] = *(const half8*)&sm.wsh[(32 + et*16 + L15)*36 + quad*8];
        bwv[et] = *(const half8*)&sm.wsh[(64 + et*16 + L15)*36 + quad*8];
        float bv = sm.bsh[64 + et*16 + L15];
        cv[et] = (floatx4){bv,bv,bv,bv};
    }

    _Float16* qs = sm.u.a.Kst[1];   // alias: dead once bq frag is read

    half4 vown[2];      // own rows' V for the MLP input (no LDS round-trip)
    float4 xf0, xf1;    // single prefetch slot (wave projects 16 rows/tile)
    auto prefetch = [&](int tile) {
        const float* p = x + ((size_t)b*N_ + tile*128 + w*16 + L15)*64 + g*32 + quad*8;
        xf0 = *(const float4*)p;
        xf1 = *(const float4*)(p + 4);
    };
    // K/V projection of the prefetched tile; interleaved per-et to keep
    // transient register pressure low (compute 2 MFMAs -> pack -> store).
    auto proj_tile = [&](int buf) {
        half8 ax = cvt8(xf0, xf1);
        int rb = w*16 + quad*4;
        #pragma unroll
        for (int et = 0; et < 2; et++) {
            floatx4 dk = MFMA32(ax, bwk[et], zz, 0,0,0);
            floatx4 dv = MFMA32(ax, bwv[et], cv[et], 0,0,0);
            half2 k01 = pkcvt(dk[0], dk[1]);
            half2 k23 = pkcvt(dk[2], dk[3]);
            sm.u.a.Kst[buf][(rb+0)*36 + et*16 + L15] = k01[0];
            sm.u.a.Kst[buf][(rb+1)*36 + et*16 + L15] = k01[1];
            sm.u.a.Kst[buf][(rb+2)*36 + et*16 + L15] = k23[0];
            sm.u.a.Kst[buf][(rb+3)*36 + et*16 + L15] = k23[1];
            half2 v01 = pkcvt(dv[0], dv[1]);
            half2 v23 = pkcvt(dv[2], dv[3]);
            half4 vh = { v01[0], v01[1], v23[0], v23[1] };
            *(half4*)&sm.u.a.Vtst[buf][(et*16 + L15)*136 + rb] = vh;
        }
    };

    // ---- prologue: tile qtile -> Q (qs + vown) and K/V (buf 0) in ONE pass ----
    prefetch(qtile);
    {
        half8 ax = cvt8(xf0, xf1);
        int rb = w*16 + quad*4;
        #pragma unroll
        for (int et = 0; et < 2; et++) {
            float bq = sm.bsh[et*16 + L15] * QSC;
            floatx4 cq = {bq,bq,bq,bq};
            floatx4 dq = MFMA32(ax, bwq[et], cq, 0,0,0);
            floatx4 dk = MFMA32(ax, bwk[et], zz, 0,0,0);
            floatx4 dv = MFMA32(ax, bwv[et], cv[et], 0,0,0);
            #pragma unroll
            for (int r = 0; r < 4; r++)
                qs[(rb+r)*36 + et*16 + L15] = (_Float16)dq[r];
            half2 k01 = pkcvt(dk[0], dk[1]);
            half2 k23 = pkcvt(dk[2], dk[3]);
            sm.u.a.Kst[0][(rb+0)*36 + et*16 + L15] = k01[0];
            sm.u.a.Kst[0][(rb+1)*36 + et*16 + L15] = k01[1];
            sm.u.a.Kst[0][(rb+2)*36 + et*16 + L15] = k23[0];
            sm.u.a.Kst[0][(rb+3)*36 + et*16 + L15] = k23[1];
            half2 v01 = pkcvt(dv[0], dv[1]);
            half2 v23 = pkcvt(dv[2], dv[3]);
            half4 vh = { v01[0], v01[1], v23[0], v23[1] };
            *(half4*)&sm.u.a.Vtst[0][(et*16 + L15)*136 + rb] = vh;
            vown[et] = vh;
        }
    }
    // bq frag: wave reads ONLY rows w*16..w*16+15, which it just wrote ->
    // in-wave DS ordering makes this safe before the barrier; the barrier
    // then protects Kst[1] (first written by proj_tile in loop iter 0).
    half8 bq0 = *(const half8*)&qs[(w*16 + L15)*36 + quad*8];
    __syncthreads();

    floatx4 o00 = zz, o01 = zz;
    float lsum0 = 0.f;

    // ---- k-loop, physically starting at qtile (softmax sum order-invariant) ----
    for (int kt = 0; kt < 8; kt++) {
        int cur = kt & 1;
        if (kt < 7) prefetch((qtile + kt + 1) & 7);
        __builtin_amdgcn_s_setprio(1);
        #pragma unroll
        for (int m8 = 0; m8 < 8; m8++) {
            half8 ak = *(const half8*)&sm.u.a.Kst[cur][(m8*16 + L15)*36 + quad*8];
            floatx4 s0 = MFMA32(ak, bq0, zz, 0,0,0);
            float p00 = EXP2(s0.x), p01 = EXP2(s0.y), p02 = EXP2(s0.z), p03 = EXP2(s0.w);
            lsum0 += (p00+p01)+(p02+p03);
            half2 pa = pkcvt(p00, p01);
            half2 pb = pkcvt(p02, p03);
            half4 a0 = { pa[0], pa[1], pb[0], pb[1] };
            half4 bv0 = *(const half4*)&sm.u.a.Vtst[cur][      L15*136 + m8*16 + quad*4];
            half4 bv1 = *(const half4*)&sm.u.a.Vtst[cur][(16 + L15)*136 + m8*16 + quad*4];
            o00 = MFMA16(a0, bv0, o00, 0,0,0);
            o01 = MFMA16(a0, bv1, o01, 0,0,0);
        }
        __builtin_amdgcn_s_setprio(0);
        if (kt < 7) {
            proj_tile(1 - cur);
            __syncthreads();
        }
    }
    __syncthreads();   // all waves done reading Kst/Vtst before xs (alias) writes

    // ---- softmax denominators: fold quads, per-row inverses via shuffles ----
    lsum0 += __shfl_xor(lsum0, 16, 64);
    lsum0 += __shfl_xor(lsum0, 32, 64);
    float inv0 = 1.0f / lsum0;   // row w*16 + L15 (all lanes)
    float li[4];
    #pragma unroll
    for (int r = 0; r < 4; r++)
        li[r] = __shfl(inv0, quad*4 + r, 64);

    // ---- xs: v-part from vown regs, attn-part from O regs (rows wave-private) ----
    {
        int rb = w*16 + quad*4;
        #pragma unroll
        for (int et = 0; et < 2; et++) {
            #pragma unroll
            for (int r = 0; r < 4; r++)
                sm.u.xs[(rb+r)*72 + et*16 + L15] = vown[et][r];
            floatx4 ov = et ? o01 : o00;
            sm.u.xs[(rb+0)*72 + 32 + et*16 + L15] = (_Float16)(ov[0]*li[0]);
            sm.u.xs[(rb+1)*72 + 32 + et*16 + L15] = (_Float16)(ov[1]*li[1]);
            sm.u.xs[(rb+2)*72 + 32 + et*16 + L15] = (_Float16)(ov[2]*li[2]);
            sm.u.xs[(rb+3)*72 + 32 + et*16 + L15] = (_Float16)(ov[3]*li[3]);
        }
    }

    // ---- MLP weight A-frags: A[m=o=mt*16+L15][k=i=quad*4+j] ----
    half4 a1f[2][4], a2f[2][2], a3f[2][2];
    #pragma unroll
    for (int mt = 0; mt < 2; mt++) {
        #pragma unroll
        for (int kt = 0; kt < 4; kt++) {
            float4 f = *(const float4*)(w_h1 + (size_t)(g*32+mt*16+L15)*64 + kt*16 + quad*4);
            half2 ha = pkcvt(f.x, f.y);
            half2 hb = pkcvt(f.z, f.w);
            half4 h = { ha[0], ha[1], hb[0], hb[1] };
            a1f[mt][kt] = h;
        }
        #pragma unroll
        for (int kt = 0; kt < 2; kt++) {
            float4 f = *(const float4*)(w_h10 + (size_t)(g*32+mt*16+L15)*32 + kt*16 + quad*4);
            half2 ha = pkcvt(f.x, f.y);
            half2 hb = pkcvt(f.z, f.w);
            half4 h = { ha[0], ha[1], hb[0], hb[1] };
            a2f[mt][kt] = h;
            float4 f2 = *(const float4*)(w_h11 + (size_t)(g*32+mt*16+L15)*32 + kt*16 + quad*4);
            half2 hc = pkcvt(f2.x, f2.y);
            half2 hd = pkcvt(f2.z, f2.w);
            half4 h2 = { hc[0], hc[1], hd[0], hd[1] };
            a3f[mt][kt] = h2;
        }
    }

    // ---- layer 1 (bias-seeded): D[o=32][q=16] for this wave's 16 rows ----
    floatx4 d1[2];
    #pragma unroll
    for (int mt = 0; mt < 2; mt++) {
        float4 bb = *(const float4*)&sm.bl1[mt*16 + quad*4];
        d1[mt] = (floatx4){bb.x, bb.y, bb.z, bb.w};
    }
    #pragma unroll
    for (int kt = 0; kt < 4; kt++) {
        half4 b1 = *(const half4*)&sm.u.xs[(w*16 + L15)*72 + kt*16 + quad*4];
        d1[0] = MFMA16(a1f[0][kt], b1, d1[0], 0,0,0);
        d1[1] = MFMA16(a1f[1][kt], b1, d1[1], 0,0,0);
    }
    half4 h1b[2];   // C layout == next layer's B layout: in-register chain
    #pragma unroll
    for (int mt = 0; mt < 2; mt++) {
        float v0 = d1[mt][0]; v0 = (v0>=0.f)?v0:NEG*v0;
        float v1 = d1[mt][1]; v1 = (v1>=0.f)?v1:NEG*v1;
        float v2 = d1[mt][2]; v2 = (v2>=0.f)?v2:NEG*v2;
        float v3 = d1[mt][3]; v3 = (v3>=0.f)?v3:NEG*v3;
        half2 ha = pkcvt(v0, v1);
        half2 hb = pkcvt(v2, v3);
        half4 h = { ha[0], ha[1], hb[0], hb[1] };
        h1b[mt] = h;
    }
    floatx4 d2[2];
    #pragma unroll
    for (int mt = 0; mt < 2; mt++) {
        float4 bb = *(const float4*)&sm.bl10[mt*16 + quad*4];
        d2[mt] = (floatx4){bb.x, bb.y, bb.z, bb.w};
        #pragma unroll
        for (int kt = 0; kt < 2; kt++)
            d2[mt] = MFMA16(a2f[mt][kt], h1b[kt], d2[mt], 0,0,0);
    }
    half4 h2b[2];
    #pragma unroll
    for (int mt = 0; mt < 2; mt++) {
        float v0 = d2[mt][0]; v0 = (v0>=0.f)?v0:NEG*v0;
        float v1 = d2[mt][1]; v1 = (v1>=0.f)?v1:NEG*v1;
        float v2 = d2[mt][2]; v2 = (v2>=0.f)?v2:NEG*v2;
        float v3 = d2[mt][3]; v3 = (v3>=0.f)?v3:NEG*v3;
        half2 ha = pkcvt(v0, v1);
        half2 hb = pkcvt(v2, v3);
        half4 h = { ha[0], ha[1], hb[0], hb[1] };
        h2b[mt] = h;
    }
    floatx4 d3[2];
    #pragma unroll
    for (int mt = 0; mt < 2; mt++) {
        float4 bb = *(const float4*)&sm.bl11[mt*16 + quad*4];
        d3[mt] = (floatx4){bb.x, bb.y, bb.z, bb.w};
        #pragma unroll
        for (int kt = 0; kt < 2; kt++)
            d3[mt] = MFMA16(a3f[mt][kt], h2b[kt], d3[mt], 0,0,0);
    }
    // store: lane holds out[q=qbase+w*16+L15][o=mt*16+quad*4+r] -> float4
    #pragma unroll
    for (int mt = 0; mt < 2; mt++) {
        float4 ov;
        ov.x = d3[mt][0]; ov.x = (ov.x>=0.f)?ov.x:NEG*ov.x;
        ov.y = d3[mt][1]; ov.y = (ov.y>=0.f)?ov.y:NEG*ov.y;
        ov.z = d3[mt][2]; ov.z = (ov.z>=0.f)?ov.z:NEG*ov.z;
        ov.w = d3[mt][3]; ov.w = (ov.w>=0.f)?ov.w:NEG*ov.w;
        *(float4*)(out + ((size_t)b*N_ + qbase + w*16 + L15)*64 + g*32 + mt*16 + quad*4) = ov;
    }
}

extern "C" void kernel_launch(void* const* d_in, const int* in_sizes, int n_in,
                              void* d_out, int out_size, void* d_ws, size_t ws_size,
                              hipStream_t stream) {
    const float* x_e   = (const float*)d_in[0];
    const float* w_qkv = (const float*)d_in[1];
    const float* b_qkv = (const float*)d_in[2];
    const float* w_h1  = (const float*)d_in[3];
    const float* b_h1  = (const float*)d_in[4];
    const float* w_h10 = (const float*)d_in[5];
    const float* b_h10 = (const float*)d_in[6];
    const float* w_h11 = (const float*)d_in[7];
    const float* b_h11 = (const float*)d_in[8];
    float* out = (float*)d_out;

    hipLaunchKernelGGL(fused_kernel, dim3(B_*2*8), dim3(512), 0, stream,
                       x_e, w_qkv, b_qkv, w_h1, b_h1, w_h10, b_h10, w_h11, b_h11, out);
}

// Round 11
// 98.396 us; speedup vs baseline: 1.0264x; 1.0264x over previous
//
#include <hip/hip_runtime.h>

#define B_ 32
#define N_ 1024
#define NEG 0.01f
#define QSC (1.4426950408889634f/32.0f)   // log2(e)/E folded into staged Wq/bq

using half8  = __attribute__((ext_vector_type(8))) _Float16;
using half4  = __attribute__((ext_vector_type(4))) _Float16;
using half2  = __attribute__((ext_vector_type(2))) _Float16;
using fp16x2 = __attribute__((ext_vector_type(2))) __fp16;
using floatx4 = __attribute__((ext_vector_type(4))) float;

#if defined(__has_builtin)
#if __has_builtin(__builtin_amdgcn_exp2f)
#define EXP2(x) __builtin_amdgcn_exp2f(x)
#endif
#endif
#ifndef EXP2
#define EXP2(x) exp2f(x)
#endif

#define MFMA32 __builtin_amdgcn_mfma_f32_16x16x32_f16
#define MFMA16 __builtin_amdgcn_mfma_f32_16x16x16f16

__device__ inline half2 pkcvt(float a, float b) {
    fp16x2 r = __builtin_amdgcn_cvt_pkrtz(a, b);
    return __builtin_bit_cast(half2, r);
}

__device__ inline half8 cvt8(float4 a, float4 b) {
    half2 p0 = pkcvt(a.x, a.y);
    half2 p1 = pkcvt(a.z, a.w);
    half2 p2 = pkcvt(b.x, b.y);
    half2 p3 = pkcvt(b.z, b.w);
    half8 h = { p0[0],p0[1], p1[0],p1[1], p2[0],p2[1], p3[0],p3[1] };
    return h;
}

// Round-9 base (4 waves x 32 q-rows, 97.85us) with ONE change: the K/V
// projection of tile t+1 is issued at the TOP of iteration t (before the
// attention loop), with a 2-tile-deep x prefetch. Proj's MFMA latency and
// 20 LDS writes drain under ~1000 cycles of attention issue instead of
// sitting on the post-attention critical path at the barrier.
// Race-free with the same 1 barrier/tile: buf[1-cur]'s last readers are
// iteration kt-1's attention, separated by kt-1's barrier.
struct __align__(16) Smem {
    _Float16 wsh[96*36];       // 6912B: Wq(pre-scaled)/Wk/Wv, stride 36
    float    bsh[96];          // 384B
    union {
        struct {
            _Float16 Kst[2][128*36];   // ping-pong K tile [kpos][e]; Kst[1]=qs pre-loop
            _Float16 Vtst[2][32*136];  // ping-pong Vt tile [e][kpos]
        } a;
        _Float16 xs[128*72];           // epilogue MLP input [q][ v(32) | attn(32) ]
    } u;
    float bl1[32], bl10[32], bl11[32];
};  // 43520 B

__global__ __launch_bounds__(256, 2) void fused_kernel(
    const float* __restrict__ x, const float* __restrict__ w_qkv, const float* __restrict__ b_qkv,
    const float* __restrict__ w_h1,  const float* __restrict__ b_h1,
    const float* __restrict__ w_h10, const float* __restrict__ b_h10,
    const float* __restrict__ w_h11, const float* __restrict__ b_h11,
    float* __restrict__ out)
{
    __shared__ Smem sm;
    int t = threadIdx.x;
    int bid = blockIdx.x;
    // XCD-affine remap: all 8 q-tile blocks of one bg land on the same XCD
    int xcd = bid & 7, j = bid >> 3;
    int bg = xcd*8 + (j >> 3);
    int qtile = j & 7;
    int b = bg >> 1, g = bg & 1;
    int qbase = qtile * 128;
    int lane = t & 63, w = t >> 6;
    int L15 = lane & 15, quad = lane >> 4;
    const floatx4 zz = {0.f,0.f,0.f,0.f};

    // ---- stage qkv weights (Q rows pre-scaled by QSC) + biases ----
    for (int idx = t; idx < 96*32; idx += 256) {
        int r = idx >> 5, c = idx & 31;
        float wv = w_qkv[(g*96 + r)*32 + c];
        sm.wsh[r*36 + c] = (_Float16)(r < 32 ? wv*QSC : wv);
    }
    if (t < 96) sm.bsh[t] = b_qkv[g*96 + t];
    if (t < 32) {
        sm.bl1[t]  = b_h1[g*32+t];
        sm.bl10[t] = b_h10[g*32+t];
        sm.bl11[t] = b_h11[g*32+t];
    }
    __syncthreads();

    // ---- weight B-frags + bias seeds (K bias dropped: shift-invariant) ----
    half8 bwq[2], bwk[2], bwv[2];
    floatx4 cv[2];
    #pragma unroll
    for (int et = 0; et < 2; et++) {
        bwq[et] = *(const half8*)&sm.wsh[(     et*16 + L15)*36 + quad*8];
        bwk[et] = *(const half8*)&sm.wsh[(32 + et*16 + L15)*36 + quad*8];
        bwv[et] = *(const half8*)&sm.wsh[(64 + et*16 + L15)*36 + quad*8];
        float bv = sm.bsh[64 + et*16 + L15];
        cv[et] = (floatx4){bv,bv,bv,bv};
    }

    _Float16* qs = sm.u.a.Kst[1];   // alias: dead once bq frags are read

    half4 vown[2][2];   // own rows' V for the MLP input (no LDS round-trip)
    float4 xf0[2], xf1[2];
    auto prefetch = [&](int tile) {
        #pragma unroll
        for (int mt = 0; mt < 2; mt++) {
            const float* p = x + ((size_t)b*N_ + tile*128 + w*32 + mt*16 + L15)*64 + g*32 + quad*8;
            xf0[mt] = *(const float4*)p;
            xf1[mt] = *(const float4*)(p + 4);
        }
    };
    // K/V projection of the tile held in xf; interleaved per-(mt,et) to keep
    // transient register pressure low (compute 2 MFMAs -> pack -> store).
    auto proj_tile = [&](int buf) {
        #pragma unroll
        for (int mt = 0; mt < 2; mt++) {
            half8 ax = cvt8(xf0[mt], xf1[mt]);
            int rb = w*32 + mt*16 + quad*4;
            #pragma unroll
            for (int et = 0; et < 2; et++) {
                floatx4 dk = MFMA32(ax, bwk[et], zz, 0,0,0);
                floatx4 dv = MFMA32(ax, bwv[et], cv[et], 0,0,0);
                half2 k01 = pkcvt(dk[0], dk[1]);
                half2 k23 = pkcvt(dk[2], dk[3]);
                sm.u.a.Kst[buf][(rb+0)*36 + et*16 + L15] = k01[0];
                sm.u.a.Kst[buf][(rb+1)*36 + et*16 + L15] = k01[1];
                sm.u.a.Kst[buf][(rb+2)*36 + et*16 + L15] = k23[0];
                sm.u.a.Kst[buf][(rb+3)*36 + et*16 + L15] = k23[1];
                half2 v01 = pkcvt(dv[0], dv[1]);
                half2 v23 = pkcvt(dv[2], dv[3]);
                half4 vh = { v01[0], v01[1], v23[0], v23[1] };
                *(half4*)&sm.u.a.Vtst[buf][(et*16 + L15)*136 + rb] = vh;
            }
        }
    };

    // ---- prologue: tile qtile -> Q (qs + vown) and K/V (buf 0) in ONE pass ----
    prefetch(qtile);
    #pragma unroll
    for (int mt = 0; mt < 2; mt++) {
        half8 ax = cvt8(xf0[mt], xf1[mt]);
        int rb = w*32 + mt*16 + quad*4;
        #pragma unroll
        for (int et = 0; et < 2; et++) {
            float bq = sm.bsh[et*16 + L15] * QSC;
            floatx4 cq = {bq,bq,bq,bq};
            floatx4 dq = MFMA32(ax, bwq[et], cq, 0,0,0);
            floatx4 dk = MFMA32(ax, bwk[et], zz, 0,0,0);
            floatx4 dv = MFMA32(ax, bwv[et], cv[et], 0,0,0);
            #pragma unroll
            for (int r = 0; r < 4; r++)
                qs[(rb+r)*36 + et*16 + L15] = (_Float16)dq[r];
            half2 k01 = pkcvt(dk[0], dk[1]);
            half2 k23 = pkcvt(dk[2], dk[3]);
            sm.u.a.Kst[0][(rb+0)*36 + et*16 + L15] = k01[0];
            sm.u.a.Kst[0][(rb+1)*36 + et*16 + L15] = k01[1];
            sm.u.a.Kst[0][(rb+2)*36 + et*16 + L15] = k23[0];
            sm.u.a.Kst[0][(rb+3)*36 + et*16 + L15] = k23[1];
            half2 v01 = pkcvt(dv[0], dv[1]);
            half2 v23 = pkcvt(dv[2], dv[3]);
            half4 vh = { v01[0], v01[1], v23[0], v23[1] };
            *(half4*)&sm.u.a.Vtst[0][(et*16 + L15)*136 + rb] = vh;
            vown[mt][et] = vh;
        }
    }
    // bq frags: wave w reads ONLY rows it just wrote (in-wave DS ordering) ->
    // safe before the barrier; the barrier then protects Kst[1] (= qs alias),
    // first written by proj_tile in loop iter 0.
    half8 bq0 = *(const half8*)&qs[(w*32 +      L15)*36 + quad*8];
    half8 bq1 = *(const half8*)&qs[(w*32 + 16 + L15)*36 + quad*8];
    prefetch((qtile + 1) & 7);   // xf = tile qtile+1, consumed by kt=0's proj
    __syncthreads();

    floatx4 o00 = zz, o01 = zz, o10 = zz, o11 = zz;
    float lsum0 = 0.f, lsum1 = 0.f;

    // ---- k-loop, starting at qtile; proj FIRST (overlapped by attention) ----
    for (int kt = 0; kt < 8; kt++) {
        int cur = kt & 1;
        if (kt < 7) proj_tile(1 - cur);            // consumes xf (tile qtile+kt+1)
        if (kt < 6) prefetch((qtile + kt + 2) & 7); // refill xf for next proj
        __builtin_amdgcn_s_setprio(1);
        #pragma unroll
        for (int m8 = 0; m8 < 8; m8++) {
            half8 ak = *(const half8*)&sm.u.a.Kst[cur][(m8*16 + L15)*36 + quad*8];
            floatx4 s0 = MFMA32(ak, bq0, zz, 0,0,0);
            floatx4 s1 = MFMA32(ak, bq1, zz, 0,0,0);
            float p00 = EXP2(s0.x), p01 = EXP2(s0.y), p02 = EXP2(s0.z), p03 = EXP2(s0.w);
            float p10 = EXP2(s1.x), p11 = EXP2(s1.y), p12 = EXP2(s1.z), p13 = EXP2(s1.w);
            lsum0 += (p00+p01)+(p02+p03);
            lsum1 += (p10+p11)+(p12+p13);
            half2 pa = pkcvt(p00, p01);
            half2 pb = pkcvt(p02, p03);
            half2 pc = pkcvt(p10, p11);
            half2 pd = pkcvt(p12, p13);
            half4 a0 = { pa[0], pa[1], pb[0], pb[1] };
            half4 a1 = { pc[0], pc[1], pd[0], pd[1] };
            half4 bv0 = *(const half4*)&sm.u.a.Vtst[cur][      L15*136 + m8*16 + quad*4];
            half4 bv1 = *(const half4*)&sm.u.a.Vtst[cur][(16 + L15)*136 + m8*16 + quad*4];
            o00 = MFMA16(a0, bv0, o00, 0,0,0);
            o01 = MFMA16(a0, bv1, o01, 0,0,0);
            o10 = MFMA16(a1, bv0, o10, 0,0,0);
            o11 = MFMA16(a1, bv1, o11, 0,0,0);
        }
        __builtin_amdgcn_s_setprio(0);
        __syncthreads();   // kt<7: buf swap safety; kt=7: protects xs alias below
    }

    // ---- softmax denominators: fold quads, per-row inverses via shuffles ----
    lsum0 += __shfl_xor(lsum0, 16, 64); lsum0 += __shfl_xor(lsum0, 32, 64);
    lsum1 += __shfl_xor(lsum1, 16, 64); lsum1 += __shfl_xor(lsum1, 32, 64);
    float inv0 = 1.0f / lsum0;   // row w*32 + L15 (all lanes)
    float inv1 = 1.0f / lsum1;   // row w*32 + 16 + L15
    float li[2][4];
    #pragma unroll
    for (int r = 0; r < 4; r++) {
        li[0][r] = __shfl(inv0, quad*4 + r, 64);
        li[1][r] = __shfl(inv1, quad*4 + r, 64);
    }

    // ---- xs: v-part from vown regs, attn-part from O regs (rows wave-private) ----
    {
        const floatx4* ofr[2][2] = { {&o00,&o01}, {&o10,&o11} };
        #pragma unroll
        for (int nt = 0; nt < 2; nt++) {
            int rb = w*32 + nt*16 + quad*4;
            #pragma unroll
            for (int et = 0; et < 2; et++) {
                #pragma unroll
                for (int r = 0; r < 4; r++)
                    sm.u.xs[(rb+r)*72 + et*16 + L15] = vown[nt][et][r];
                floatx4 ov = *ofr[nt][et];
                sm.u.xs[(rb+0)*72 + 32 + et*16 + L15] = (_Float16)(ov[0]*li[nt][0]);
                sm.u.xs[(rb+1)*72 + 32 + et*16 + L15] = (_Float16)(ov[1]*li[nt][1]);
                sm.u.xs[(rb+2)*72 + 32 + et*16 + L15] = (_Float16)(ov[2]*li[nt][2]);
                sm.u.xs[(rb+3)*72 + 32 + et*16 + L15] = (_Float16)(ov[3]*li[nt][3]);
            }
        }
    }

    // ---- MLP weight A-frags: A[m=o=mt*16+L15][k=i=quad*4+j] ----
    half4 a1f[2][4], a2f[2][2], a3f[2][2];
    #pragma unroll
    for (int mt = 0; mt < 2; mt++) {
        #pragma unroll
        for (int kt = 0; kt < 4; kt++) {
            float4 f = *(const float4*)(w_h1 + (size_t)(g*32+mt*16+L15)*64 + kt*16 + quad*4);
            half2 ha = pkcvt(f.x, f.y);
            half2 hb = pkcvt(f.z, f.w);
            half4 h = { ha[0], ha[1], hb[0], hb[1] };
            a1f[mt][kt] = h;
        }
        #pragma unroll
        for (int kt = 0; kt < 2; kt++) {
            float4 f = *(const float4*)(w_h10 + (size_t)(g*32+mt*16+L15)*32 + kt*16 + quad*4);
            half2 ha = pkcvt(f.x, f.y);
            half2 hb = pkcvt(f.z, f.w);
            half4 h = { ha[0], ha[1], hb[0], hb[1] };
            a2f[mt][kt] = h;
            float4 f2 = *(const float4*)(w_h11 + (size_t)(g*32+mt*16+L15)*32 + kt*16 + quad*4);
            half2 hc = pkcvt(f2.x, f2.y);
            half2 hd = pkcvt(f2.z, f2.w);
            half4 h2 = { hc[0], hc[1], hd[0], hd[1] };
            a3f[mt][kt] = h2;
        }
    }

    // ---- layer 1 (bias-seeded): D[o][q] over this wave's 32 q rows ----
    floatx4 d1[2][2];
    #pragma unroll
    for (int mt = 0; mt < 2; mt++) {
        float4 bb = *(const float4*)&sm.bl1[mt*16 + quad*4];
        floatx4 seed = { bb.x, bb.y, bb.z, bb.w };
        d1[mt][0] = seed; d1[mt][1] = seed;
    }
    #pragma unroll
    for (int nt = 0; nt < 2; nt++)
        #pragma unroll
        for (int kt = 0; kt < 4; kt++) {
            half4 b1 = *(const half4*)&sm.u.xs[(w*32+nt*16+L15)*72 + kt*16 + quad*4];
            d1[0][nt] = MFMA16(a1f[0][kt], b1, d1[0][nt], 0,0,0);
            d1[1][nt] = MFMA16(a1f[1][kt], b1, d1[1][nt], 0,0,0);
        }
    half4 h1b[2][2];   // C layout == next layer's B layout: in-register chain
    #pragma unroll
    for (int mt = 0; mt < 2; mt++)
        #pragma unroll
        for (int nt = 0; nt < 2; nt++) {
            float v0 = d1[mt][nt][0]; v0 = (v0>=0.f)?v0:NEG*v0;
            float v1 = d1[mt][nt][1]; v1 = (v1>=0.f)?v1:NEG*v1;
            float v2 = d1[mt][nt][2]; v2 = (v2>=0.f)?v2:NEG*v2;
            float v3 = d1[mt][nt][3]; v3 = (v3>=0.f)?v3:NEG*v3;
            half2 ha = pkcvt(v0, v1);
            half2 hb = pkcvt(v2, v3);
            half4 h = { ha[0], ha[1], hb[0], hb[1] };
            h1b[mt][nt] = h;
        }
    floatx4 d2[2][2];
    #pragma unroll
    for (int mt = 0; mt < 2; mt++) {
        float4 bb = *(const float4*)&sm.bl10[mt*16 + quad*4];
        floatx4 seed = { bb.x, bb.y, bb.z, bb.w };
        d2[mt][0] = seed; d2[mt][1] = seed;
    }
    #pragma unroll
    for (int mt = 0; mt < 2; mt++)
        #pragma unroll
        for (int nt = 0; nt < 2; nt++)
            #pragma unroll
            for (int kt = 0; kt < 2; kt++)
                d2[mt][nt] = MFMA16(a2f[mt][kt], h1b[kt][nt], d2[mt][nt], 0,0,0);
    half4 h2b[2][2];
    #pragma unroll
    for (int mt = 0; mt < 2; mt++)
        #pragma unroll
        for (int nt = 0; nt < 2; nt++) {
            float v0 = d2[mt][nt][0]; v0 = (v0>=0.f)?v0:NEG*v0;
            float v1 = d2[mt][nt][1]; v1 = (v1>=0.f)?v1:NEG*v1;
            float v2 = d2[mt][nt][2]; v2 = (v2>=0.f)?v2:NEG*v2;
            float v3 = d2[mt][nt][3]; v3 = (v3>=0.f)?v3:NEG*v3;
            half2 ha = pkcvt(v0, v1);
            half2 hb = pkcvt(v2, v3);
            half4 h = { ha[0], ha[1], hb[0], hb[1] };
            h2b[mt][nt] = h;
        }
    floatx4 d3[2][2];
    #pragma unroll
    for (int mt = 0; mt < 2; mt++) {
        float4 bb = *(const float4*)&sm.bl11[mt*16 + quad*4];
        floatx4 seed = { bb.x, bb.y, bb.z, bb.w };
        d3[mt][0] = seed; d3[mt][1] = seed;
    }
    #pragma unroll
    for (int mt = 0; mt < 2; mt++)
        #pragma unroll
        for (int nt = 0; nt < 2; nt++)
            #pragma unroll
            for (int kt = 0; kt < 2; kt++)
                d3[mt][nt] = MFMA16(a3f[mt][kt], h2b[kt][nt], d3[mt][nt], 0,0,0);
    // store: lane holds out[q=qbase+w*32+nt*16+L15][o=mt*16+quad*4+r] -> float4
    #pragma unroll
    for (int mt = 0; mt < 2; mt++)
        #pragma unroll
        for (int nt = 0; nt < 2; nt++) {
            float4 ov;
            ov.x = d3[mt][nt][0]; ov.x = (ov.x>=0.f)?ov.x:NEG*ov.x;
            ov.y = d3[mt][nt][1]; ov.y = (ov.y>=0.f)?ov.y:NEG*ov.y;
            ov.z = d3[mt][nt][2]; ov.z = (ov.z>=0.f)?ov.z:NEG*ov.z;
            ov.w = d3[mt][nt][3]; ov.w = (ov.w>=0.f)?ov.w:NEG*ov.w;
            *(float4*)(out + ((size_t)b*N_ + qbase + w*32 + nt*16 + L15)*64 + g*32 + mt*16 + quad*4) = ov;
        }
}

extern "C" void kernel_launch(void* const* d_in, const int* in_sizes, int n_in,
                              void* d_out, int out_size, void* d_ws, size_t ws_size,
                              hipStream_t stream) {
    const float* x_e   = (const float*)d_in[0];
    const float* w_qkv = (const float*)d_in[1];
    const float* b_qkv = (const float*)d_in[2];
    const float* w_h1  = (const float*)d_in[3];
    const float* b_h1  = (const float*)d_in[4];
    const float* w_h10 = (const float*)d_in[5];
    const float* b_h10 = (const float*)d_in[6];
    const float* w_h11 = (const float*)d_in[7];
    const float* b_h11 = (const float*)d_in[8];
    float* out = (float*)d_out;

    hipLaunchKernelGGL(fused_kernel, dim3(B_*2*8), dim3(256), 0, stream,
                       x_e, w_qkv, b_qkv, w_h1, b_h1, w_h10, b_h10, w_h11, b_h11, out);
}

// Round 12
// 97.572 us; speedup vs baseline: 1.0351x; 1.0085x over previous
//
#include <hip/hip_runtime.h>

#define B_ 32
#define N_ 1024
#define NEG 0.01f
#define QSC (1.4426950408889634f/32.0f)   // log2(e)/E folded into staged Wq/bq

using half8  = __attribute__((ext_vector_type(8))) _Float16;
using half4  = __attribute__((ext_vector_type(4))) _Float16;
using half2  = __attribute__((ext_vector_type(2))) _Float16;
using fp16x2 = __attribute__((ext_vector_type(2))) __fp16;
using floatx4 = __attribute__((ext_vector_type(4))) float;

#if defined(__has_builtin)
#if __has_builtin(__builtin_amdgcn_exp2f)
#define EXP2(x) __builtin_amdgcn_exp2f(x)
#endif
#endif
#ifndef EXP2
#define EXP2(x) exp2f(x)
#endif

#define MFMA32 __builtin_amdgcn_mfma_f32_16x16x32_f16
#define MFMA16 __builtin_amdgcn_mfma_f32_16x16x16f16

__device__ inline half2 pkcvt(float a, float b) {
    fp16x2 r = __builtin_amdgcn_cvt_pkrtz(a, b);
    return __builtin_bit_cast(half2, r);
}

__device__ inline half8 cvt8(float4 a, float4 b) {
    half2 p0 = pkcvt(a.x, a.y);
    half2 p1 = pkcvt(a.z, a.w);
    half2 p2 = pkcvt(b.x, b.y);
    half2 p3 = pkcvt(b.z, b.w);
    half8 h = { p0[0],p0[1], p1[0],p1[1], p2[0],p2[1], p3[0],p3[1] };
    return h;
}

// Round-9 base with ONE lever: 4-deep LDS buffer ring -> ONE barrier per
// TWO tiles (10 -> 6 barriers). Waves may drift a full tile apart; a wave's
// proj overlaps siblings' attend. Hazard rule: buffer reuse distance is 4
// tiles, barrier every 2 -> writer and last reader always separated by a
// barrier. qs aliases Kst[3] (first written by pair-0's 2nd proj, which is
// post-barrier; bq reads are pre-barrier, in-wave).
struct __align__(16) Smem {
    _Float16 wsh[96*36];       // 6912B: Wq(pre-scaled)/Wk/Wv, stride 36
    float    bsh[96];          // 384B
    union {
        struct {
            _Float16 Kst[4][128*36];   // ring K tiles [kpos][e]; Kst[3]=qs pre-loop
            _Float16 Vtst[4][32*136];  // ring Vt tiles [e][kpos]
        } a;
        _Float16 xs[128*72];           // epilogue MLP input [q][ v(32) | attn(32) ]
    } u;
    float bl1[32], bl10[32], bl11[32];
};  // 79360 B -> 2 blocks/CU (158.7KB <= 160KB)

__global__ __launch_bounds__(256, 2) void fused_kernel(
    const float* __restrict__ x, const float* __restrict__ w_qkv, const float* __restrict__ b_qkv,
    const float* __restrict__ w_h1,  const float* __restrict__ b_h1,
    const float* __restrict__ w_h10, const float* __restrict__ b_h10,
    const float* __restrict__ w_h11, const float* __restrict__ b_h11,
    float* __restrict__ out)
{
    __shared__ Smem sm;
    int t = threadIdx.x;
    int bid = blockIdx.x;
    // XCD-affine remap: all 8 q-tile blocks of one bg land on the same XCD
    int xcd = bid & 7, j = bid >> 3;
    int bg = xcd*8 + (j >> 3);
    int qtile = j & 7;
    int b = bg >> 1, g = bg & 1;
    int qbase = qtile * 128;
    int lane = t & 63, w = t >> 6;
    int L15 = lane & 15, quad = lane >> 4;
    const floatx4 zz = {0.f,0.f,0.f,0.f};

    // ---- stage qkv weights (Q rows pre-scaled by QSC) + biases ----
    for (int idx = t; idx < 96*32; idx += 256) {
        int r = idx >> 5, c = idx & 31;
        float wv = w_qkv[(g*96 + r)*32 + c];
        sm.wsh[r*36 + c] = (_Float16)(r < 32 ? wv*QSC : wv);
    }
    if (t < 96) sm.bsh[t] = b_qkv[g*96 + t];
    if (t < 32) {
        sm.bl1[t]  = b_h1[g*32+t];
        sm.bl10[t] = b_h10[g*32+t];
        sm.bl11[t] = b_h11[g*32+t];
    }
    __syncthreads();

    // ---- weight B-frags + bias seeds (K bias dropped: shift-invariant) ----
    half8 bwq[2], bwk[2], bwv[2];
    floatx4 cv[2];
    #pragma unroll
    for (int et = 0; et < 2; et++) {
        bwq[et] = *(const half8*)&sm.wsh[(     et*16 + L15)*36 + quad*8];
        bwk[et] = *(const half8*)&sm.wsh[(32 + et*16 + L15)*36 + quad*8];
        bwv[et] = *(const half8*)&sm.wsh[(64 + et*16 + L15)*36 + quad*8];
        float bv = sm.bsh[64 + et*16 + L15];
        cv[et] = (floatx4){bv,bv,bv,bv};
    }

    _Float16* qs = sm.u.a.Kst[3];   // alias: dead once bq frags are read

    half4 vown[2][2];   // own rows' V for the MLP input (no LDS round-trip)
    float4 xf0[2], xf1[2];
    auto prefetch = [&](int tile) {
        #pragma unroll
        for (int mt = 0; mt < 2; mt++) {
            const float* p = x + ((size_t)b*N_ + tile*128 + w*32 + mt*16 + L15)*64 + g*32 + quad*8;
            xf0[mt] = *(const float4*)p;
            xf1[mt] = *(const float4*)(p + 4);
        }
    };
    // K/V projection of the tile held in xf; interleaved per-(mt,et) to keep
    // transient register pressure low (compute 2 MFMAs -> pack -> store).
    auto proj_tile = [&](int buf) {
        #pragma unroll
        for (int mt = 0; mt < 2; mt++) {
            half8 ax = cvt8(xf0[mt], xf1[mt]);
            int rb = w*32 + mt*16 + quad*4;
            #pragma unroll
            for (int et = 0; et < 2; et++) {
                floatx4 dk = MFMA32(ax, bwk[et], zz, 0,0,0);
                floatx4 dv = MFMA32(ax, bwv[et], cv[et], 0,0,0);
                half2 k01 = pkcvt(dk[0], dk[1]);
                half2 k23 = pkcvt(dk[2], dk[3]);
                sm.u.a.Kst[buf][(rb+0)*36 + et*16 + L15] = k01[0];
                sm.u.a.Kst[buf][(rb+1)*36 + et*16 + L15] = k01[1];
                sm.u.a.Kst[buf][(rb+2)*36 + et*16 + L15] = k23[0];
                sm.u.a.Kst[buf][(rb+3)*36 + et*16 + L15] = k23[1];
                half2 v01 = pkcvt(dv[0], dv[1]);
                half2 v23 = pkcvt(dv[2], dv[3]);
                half4 vh = { v01[0], v01[1], v23[0], v23[1] };
                *(half4*)&sm.u.a.Vtst[buf][(et*16 + L15)*136 + rb] = vh;
            }
        }
    };

    // ---- prologue: tile qtile -> Q (qs=Kst[3] + vown) and K/V (buf 0) ----
    prefetch(qtile);
    #pragma unroll
    for (int mt = 0; mt < 2; mt++) {
        half8 ax = cvt8(xf0[mt], xf1[mt]);
        int rb = w*32 + mt*16 + quad*4;
        #pragma unroll
        for (int et = 0; et < 2; et++) {
            float bq = sm.bsh[et*16 + L15] * QSC;
            floatx4 cq = {bq,bq,bq,bq};
            floatx4 dq = MFMA32(ax, bwq[et], cq, 0,0,0);
            floatx4 dk = MFMA32(ax, bwk[et], zz, 0,0,0);
            floatx4 dv = MFMA32(ax, bwv[et], cv[et], 0,0,0);
            #pragma unroll
            for (int r = 0; r < 4; r++)
                qs[(rb+r)*36 + et*16 + L15] = (_Float16)dq[r];
            half2 k01 = pkcvt(dk[0], dk[1]);
            half2 k23 = pkcvt(dk[2], dk[3]);
            sm.u.a.Kst[0][(rb+0)*36 + et*16 + L15] = k01[0];
            sm.u.a.Kst[0][(rb+1)*36 + et*16 + L15] = k01[1];
            sm.u.a.Kst[0][(rb+2)*36 + et*16 + L15] = k23[0];
            sm.u.a.Kst[0][(rb+3)*36 + et*16 + L15] = k23[1];
            half2 v01 = pkcvt(dv[0], dv[1]);
            half2 v23 = pkcvt(dv[2], dv[3]);
            half4 vh = { v01[0], v01[1], v23[0], v23[1] };
            *(half4*)&sm.u.a.Vtst[0][(et*16 + L15)*136 + rb] = vh;
            vown[mt][et] = vh;
        }
    }
    // tile qtile+1 -> buf 1 (writes Kst[1]/Vtst[1]; qs region untouched)
    prefetch((qtile + 1) & 7);
    proj_tile(1);
    // bq frags: wave reads ONLY rows it wrote in the merged pass (in-wave DS
    // ordering); Kst[3] is next written by pair-0's 2nd proj, post-barrier.
    half8 bq0 = *(const half8*)&qs[(w*32 +      L15)*36 + quad*8];
    half8 bq1 = *(const half8*)&qs[(w*32 + 16 + L15)*36 + quad*8];
    __syncthreads();

    floatx4 o00 = zz, o01 = zz, o10 = zz, o11 = zz;
    float lsum0 = 0.f, lsum1 = 0.f;

    // ---- main loop: 4 pairs; ONE barrier per pair (2 tiles) ----
    for (int p = 0; p < 4; p++) {
        if (p < 3) prefetch((qtile + 2*p + 2) & 7);
        #pragma unroll
        for (int half_ = 0; half_ < 2; half_++) {
            int cur = (2*p + half_) & 3;
            __builtin_amdgcn_s_setprio(1);
            #pragma unroll
            for (int m8 = 0; m8 < 8; m8++) {
                half8 ak = *(const half8*)&sm.u.a.Kst[cur][(m8*16 + L15)*36 + quad*8];
                floatx4 s0 = MFMA32(ak, bq0, zz, 0,0,0);
                floatx4 s1 = MFMA32(ak, bq1, zz, 0,0,0);
                float p00 = EXP2(s0.x), p01 = EXP2(s0.y), p02 = EXP2(s0.z), p03 = EXP2(s0.w);
                float p10 = EXP2(s1.x), p11 = EXP2(s1.y), p12 = EXP2(s1.z), p13 = EXP2(s1.w);
                lsum0 += (p00+p01)+(p02+p03);
                lsum1 += (p10+p11)+(p12+p13);
                half2 pa = pkcvt(p00, p01);
                half2 pb = pkcvt(p02, p03);
                half2 pc = pkcvt(p10, p11);
                half2 pd = pkcvt(p12, p13);
                half4 a0 = { pa[0], pa[1], pb[0], pb[1] };
                half4 a1 = { pc[0], pc[1], pd[0], pd[1] };
                half4 bv0 = *(const half4*)&sm.u.a.Vtst[cur][      L15*136 + m8*16 + quad*4];
                half4 bv1 = *(const half4*)&sm.u.a.Vtst[cur][(16 + L15)*136 + m8*16 + quad*4];
                o00 = MFMA16(a0, bv0, o00, 0,0,0);
                o01 = MFMA16(a0, bv1, o01, 0,0,0);
                o10 = MFMA16(a1, bv0, o10, 0,0,0);
                o11 = MFMA16(a1, bv1, o11, 0,0,0);
            }
            __builtin_amdgcn_s_setprio(0);
            if (p < 3) {
                proj_tile((2*p + 2 + half_) & 3);   // reuse distance 4, barrier 1 ago
                if (half_ == 0) prefetch((qtile + 2*p + 3) & 7);
            }
        }
        __syncthreads();   // one barrier per 2 tiles; p=3's also guards xs alias
    }

    // ---- softmax denominators: fold quads, per-row inverses via shuffles ----
    lsum0 += __shfl_xor(lsum0, 16, 64); lsum0 += __shfl_xor(lsum0, 32, 64);
    lsum1 += __shfl_xor(lsum1, 16, 64); lsum1 += __shfl_xor(lsum1, 32, 64);
    float inv0 = 1.0f / lsum0;   // row w*32 + L15 (all lanes)
    float inv1 = 1.0f / lsum1;   // row w*32 + 16 + L15
    float li[2][4];
    #pragma unroll
    for (int r = 0; r < 4; r++) {
        li[0][r] = __shfl(inv0, quad*4 + r, 64);
        li[1][r] = __shfl(inv1, quad*4 + r, 64);
    }

    // ---- xs: v-part from vown regs, attn-part from O regs (rows wave-private) ----
    {
        const floatx4* ofr[2][2] = { {&o00,&o01}, {&o10,&o11} };
        #pragma unroll
        for (int nt = 0; nt < 2; nt++) {
            int rb = w*32 + nt*16 + quad*4;
            #pragma unroll
            for (int et = 0; et < 2; et++) {
                #pragma unroll
                for (int r = 0; r < 4; r++)
                    sm.u.xs[(rb+r)*72 + et*16 + L15] = vown[nt][et][r];
                floatx4 ov = *ofr[nt][et];
                sm.u.xs[(rb+0)*72 + 32 + et*16 + L15] = (_Float16)(ov[0]*li[nt][0]);
                sm.u.xs[(rb+1)*72 + 32 + et*16 + L15] = (_Float16)(ov[1]*li[nt][1]);
                sm.u.xs[(rb+2)*72 + 32 + et*16 + L15] = (_Float16)(ov[2]*li[nt][2]);
                sm.u.xs[(rb+3)*72 + 32 + et*16 + L15] = (_Float16)(ov[3]*li[nt][3]);
            }
        }
    }

    // ---- MLP weight A-frags: A[m=o=mt*16+L15][k=i=quad*4+j] ----
    half4 a1f[2][4], a2f[2][2], a3f[2][2];
    #pragma unroll
    for (int mt = 0; mt < 2; mt++) {
        #pragma unroll
        for (int kt = 0; kt < 4; kt++) {
            float4 f = *(const float4*)(w_h1 + (size_t)(g*32+mt*16+L15)*64 + kt*16 + quad*4);
            half2 ha = pkcvt(f.x, f.y);
            half2 hb = pkcvt(f.z, f.w);
            half4 h = { ha[0], ha[1], hb[0], hb[1] };
            a1f[mt][kt] = h;
        }
        #pragma unroll
        for (int kt = 0; kt < 2; kt++) {
            float4 f = *(const float4*)(w_h10 + (size_t)(g*32+mt*16+L15)*32 + kt*16 + quad*4);
            half2 ha = pkcvt(f.x, f.y);
            half2 hb = pkcvt(f.z, f.w);
            half4 h = { ha[0], ha[1], hb[0], hb[1] };
            a2f[mt][kt] = h;
            float4 f2 = *(const float4*)(w_h11 + (size_t)(g*32+mt*16+L15)*32 + kt*16 + quad*4);
            half2 hc = pkcvt(f2.x, f2.y);
            half2 hd = pkcvt(f2.z, f2.w);
            half4 h2 = { hc[0], hc[1], hd[0], hd[1] };
            a3f[mt][kt] = h2;
        }
    }

    // ---- layer 1 (bias-seeded): D[o][q] over this wave's 32 q rows ----
    floatx4 d1[2][2];
    #pragma unroll
    for (int mt = 0; mt < 2; mt++) {
        float4 bb = *(const float4*)&sm.bl1[mt*16 + quad*4];
        floatx4 seed = { bb.x, bb.y, bb.z, bb.w };
        d1[mt][0] = seed; d1[mt][1] = seed;
    }
    #pragma unroll
    for (int nt = 0; nt < 2; nt++)
        #pragma unroll
        for (int kt = 0; kt < 4; kt++) {
            half4 b1 = *(const half4*)&sm.u.xs[(w*32+nt*16+L15)*72 + kt*16 + quad*4];
            d1[0][nt] = MFMA16(a1f[0][kt], b1, d1[0][nt], 0,0,0);
            d1[1][nt] = MFMA16(a1f[1][kt], b1, d1[1][nt], 0,0,0);
        }
    half4 h1b[2][2];   // C layout == next layer's B layout: in-register chain
    #pragma unroll
    for (int mt = 0; mt < 2; mt++)
        #pragma unroll
        for (int nt = 0; nt < 2; nt++) {
            float v0 = d1[mt][nt][0]; v0 = (v0>=0.f)?v0:NEG*v0;
            float v1 = d1[mt][nt][1]; v1 = (v1>=0.f)?v1:NEG*v1;
            float v2 = d1[mt][nt][2]; v2 = (v2>=0.f)?v2:NEG*v2;
            float v3 = d1[mt][nt][3]; v3 = (v3>=0.f)?v3:NEG*v3;
            half2 ha = pkcvt(v0, v1);
            half2 hb = pkcvt(v2, v3);
            half4 h = { ha[0], ha[1], hb[0], hb[1] };
            h1b[mt][nt] = h;
        }
    floatx4 d2[2][2];
    #pragma unroll
    for (int mt = 0; mt < 2; mt++) {
        float4 bb = *(const float4*)&sm.bl10[mt*16 + quad*4];
        floatx4 seed = { bb.x, bb.y, bb.z, bb.w };
        d2[mt][0] = seed; d2[mt][1] = seed;
    }
    #pragma unroll
    for (int mt = 0; mt < 2; mt++)
        #pragma unroll
        for (int nt = 0; nt < 2; nt++)
            #pragma unroll
            for (int kt = 0; kt < 2; kt++)
                d2[mt][nt] = MFMA16(a2f[mt][kt], h1b[kt][nt], d2[mt][nt], 0,0,0);
    half4 h2b[2][2];
    #pragma unroll
    for (int mt = 0; mt < 2; mt++)
        #pragma unroll
        for (int nt = 0; nt < 2; nt++) {
            float v0 = d2[mt][nt][0]; v0 = (v0>=0.f)?v0:NEG*v0;
            float v1 = d2[mt][nt][1]; v1 = (v1>=0.f)?v1:NEG*v1;
            float v2 = d2[mt][nt][2]; v2 = (v2>=0.f)?v2:NEG*v2;
            float v3 = d2[mt][nt][3]; v3 = (v3>=0.f)?v3:NEG*v3;
            half2 ha = pkcvt(v0, v1);
            half2 hb = pkcvt(v2, v3);
            half4 h = { ha[0], ha[1], hb[0], hb[1] };
            h2b[mt][nt] = h;
        }
    floatx4 d3[2][2];
    #pragma unroll
    for (int mt = 0; mt < 2; mt++) {
        float4 bb = *(const float4*)&sm.bl11[mt*16 + quad*4];
        floatx4 seed = { bb.x, bb.y, bb.z, bb.w };
        d3[mt][0] = seed; d3[mt][1] = seed;
    }
    #pragma unroll
    for (int mt = 0; mt < 2; mt++)
        #pragma unroll
        for (int nt = 0; nt < 2; nt++)
            #pragma unroll
            for (int kt = 0; kt < 2; kt++)
                d3[mt][nt] = MFMA16(a3f[mt][kt], h2b[kt][nt], d3[mt][nt], 0,0,0);
    // store: lane holds out[q=qbase+w*32+nt*16+L15][o=mt*16+quad*4+r] -> float4
    #pragma unroll
    for (int mt = 0; mt < 2; mt++)
        #pragma unroll
        for (int nt = 0; nt < 2; nt++) {
            float4 ov;
            ov.x = d3[mt][nt][0]; ov.x = (ov.x>=0.f)?ov.x:NEG*ov.x;
            ov.y = d3[mt][nt][1]; ov.y = (ov.y>=0.f)?ov.y:NEG*ov.y;
            ov.z = d3[mt][nt][2]; ov.z = (ov.z>=0.f)?ov.z:NEG*ov.z;
            ov.w = d3[mt][nt][3]; ov.w = (ov.w>=0.f)?ov.w:NEG*ov.w;
            *(float4*)(out + ((size_t)b*N_ + qbase + w*32 + nt*16 + L15)*64 + g*32 + mt*16 + quad*4) = ov;
        }
}

extern "C" void kernel_launch(void* const* d_in, const int* in_sizes, int n_in,
                              void* d_out, int out_size, void* d_ws, size_t ws_size,
                              hipStream_t stream) {
    const float* x_e   = (const float*)d_in[0];
    const float* w_qkv = (const float*)d_in[1];
    const float* b_qkv = (const float*)d_in[2];
    const float* w_h1  = (const float*)d_in[3];
    const float* b_h1  = (const float*)d_in[4];
    const float* w_h10 = (const float*)d_in[5];
    const float* b_h10 = (const float*)d_in[6];
    const float* w_h11 = (const float*)d_in[7];
    const float* b_h11 = (const float*)d_in[8];
    float* out = (float*)d_out;

    hipLaunchKernelGGL(fused_kernel, dim3(B_*2*8), dim3(256), 0, stream,
                       x_e, w_qkv, b_qkv, w_h1, b_h1, w_h10, b_h10, w_h11, b_h11, out);
}